// Round 5
// baseline (1663.540 us; speedup 1.0000x reference)
//
#include <hip/hip_runtime.h>

typedef __attribute__((ext_vector_type(8))) short short8;
typedef __attribute__((ext_vector_type(4))) float f32x4;
typedef __attribute__((ext_vector_type(4))) unsigned int u32x4;
typedef unsigned short ushort_t;
typedef unsigned long long u64;

#define SEQ    256
#define BATCH  64
#define VOCAB  128
#define EMBED  256
#define HIDDEN 1024
#define NWG    64
#define JB     16
#define BH     (BATCH * HIDDEN)
#define SLOT_BYTES 131072                 // one h slot = 64x1024 bf16 = 8192 x 16B units

// workspace layout (bytes)
#define OFF_XALL 4096
#define OFF_DWBF (OFF_XALL + 3*VOCAB*HIDDEN*4)
#define OFF_HS   (OFF_DWBF + VOCAB*HIDDEN*2)     // (SEQ+1) slots, 16B-unit fragment layout

__device__ __forceinline__ ushort_t f2bf(float f) {
    unsigned u = __float_as_uint(f);
    u += 0x7FFFu + ((u >> 16) & 1u);          // RNE
    return (ushort_t)(u >> 16);
}

// 16B-unit fragment layout: unit P = ((w*4+mt)*8+ks)*64 + (q*16+la)
// holds rows mt*16+la, k = w*256 + ks*32 + q*8 + (0..7)   (8 bf16 = 16 B)
// byte offset = P*16 = w*32768 + mt*8192 + ks*1024 + (q*16+la)*16

// ---------------- init: hs[0]=bf16(hprev) frag-layout, dwbf, flags=0 ------
__global__ __launch_bounds__(256) void init_kernel(const float* __restrict__ hprev,
                                                   const float* __restrict__ dense_w,
                                                   char* __restrict__ hs,
                                                   ushort_t* __restrict__ dwbf,
                                                   unsigned* __restrict__ flags) {
    int i = blockIdx.x * 256 + threadIdx.x;
    if (i < 64) __hip_atomic_store(&flags[i], 0u, __ATOMIC_RELAXED, __HIP_MEMORY_SCOPE_AGENT);
    if (i < 8192) {
        int lane = i & 63, plane = i >> 6;
        int ks = plane & 7, mt = (plane >> 3) & 3, w = plane >> 5;
        int la = lane & 15, q = lane >> 4;
        int row = mt * 16 + la;
        int k   = w * 256 + ks * 32 + q * 8;
        const float* hp = hprev + row * HIDDEN + k;
        ushort_t* dst = (ushort_t*)(hs + (size_t)i * 16);
        #pragma unroll
        for (int e = 0; e < 8; ++e) dst[e] = f2bf(hp[e]);
    }
    if (i < VOCAB * HIDDEN) dwbf[i] = f2bf(dense_w[i]);
}

// ---------------- tables: xall[g][v][j] = emb[v]·w_g[j] + folded biases ----
__global__ __launch_bounds__(256) void tables_kernel(const float* __restrict__ emb,
    const float* __restrict__ rx_w, const float* __restrict__ rx_b, const float* __restrict__ rh_b,
    const float* __restrict__ zx_w, const float* __restrict__ zx_b, const float* __restrict__ zh_b,
    const float* __restrict__ nx_w, const float* __restrict__ nx_b,
    float* __restrict__ xall) {
    int id = blockIdx.x * 256 + threadIdx.x;          // id = (g*128+v)*1024 + j
    int j  = id & (HIDDEN - 1);
    int vg = id >> 10;
    int v  = vg & (VOCAB - 1);
    int g  = vg >> 7;
    const float* w = (g == 0 ? rx_w : (g == 1 ? zx_w : nx_w)) + j * EMBED;
    const float* e = emb + v * EMBED;
    float acc = 0.f;
    #pragma unroll 8
    for (int t = 0; t < EMBED; t += 4) {
        acc = fmaf(e[t+0], w[t+0], acc);
        acc = fmaf(e[t+1], w[t+1], acc);
        acc = fmaf(e[t+2], w[t+2], acc);
        acc = fmaf(e[t+3], w[t+3], acc);
    }
    float bias = (g == 0) ? (rx_b[j] + rh_b[j]) : ((g == 1) ? (zx_b[j] + zh_b[j]) : nx_b[j]);
    xall[id] = acc + bias;
}

// A-loads: PLAIN (L2-cached) 16B loads via inline asm — the 8 WGs on each
// XCD share the broadcast through their XCD L2 (first toucher misses to the
// device-coherent LLC where the sc1 h-stores landed; the rest hit L2).
// Inline asm keeps issue order + waitcnt placement under our control.
#define GLD(dst, base, OFF) \
    asm volatile("global_load_dwordx4 %0, %1, %2 offset:" OFF \
                 : "=v"(dst) : "v"(va), "s"(base) : "memory")

// ---------------- persistent GRU scan -------------------------------------
__global__ __launch_bounds__(256, 1) void gru_kernel(
    const int* __restrict__ x, const float* __restrict__ hprev,
    const float* __restrict__ rh_w, const float* __restrict__ zh_w,
    const float* __restrict__ nh_w, const float* __restrict__ nh_b,
    const float* __restrict__ xall,
    char* __restrict__ hs, unsigned* flags, float* __restrict__ hfin)
{
    extern __shared__ char smem[];
    float* tabs = (float*)smem;                       // [3][128][17]  26112 B
    float* hm   = tabs + 3 * VOCAB * 17;              // [64][20]       5120 B
    unsigned char* xs = (unsigned char*)(hm + BATCH * 20);   // 16384 B
    float* red  = (float*)(xs + SEQ * BATCH);         // 12288 floats  49152 B
    float* nhb  = red + 12288;                        // 16 floats

    const int tid  = threadIdx.x;
    const int wid  = tid >> 6;
    const int lane = tid & 63;
    const int jb0  = blockIdx.x * JB;
    const int la   = lane & 15;
    // WG's column region in fragment coords
    const int w0  = jb0 >> 8;
    const int ks0 = (jb0 >> 5) & 7;
    const int q0  = (jb0 >> 3) & 3;                   // 0 or 2

    // store-phase decode (tid<128): thread -> 16B unit (row smt*16+sla, 8 cols)
    const int smt = tid >> 5;                         // 0..3
    const int sqq = (tid >> 4) & 1;                   // 0..1
    const int sla = tid & 15;
    const int srow = smt * 16 + sla;
    const int sjj  = sqq * 8;                         // local col base
    const unsigned sva = (unsigned)((((w0 * 4 + smt) * 8 + ks0) * 64
                                     + (q0 + sqq) * 16 + sla) * 16);

    // A-load vaddr (byte): lane*16 + wid*32768
    const unsigned va = (unsigned)((wid << 15) | (lane << 4));

    // ---- prologue: LDS fills ----
    for (int i = tid; i < 3 * VOCAB * JB; i += 256) {
        int g = i >> 11, rem = i & 2047, v = rem >> 4, j = rem & 15;
        tabs[(g * VOCAB + v) * 17 + j] = xall[(g * VOCAB + v) * HIDDEN + jb0 + j];
    }
    for (int i = tid; i < SEQ * BATCH; i += 256) xs[i] = (unsigned char)x[i];
    for (int i = tid; i < BATCH * JB; i += 256) {
        int b = i >> 4, j = i & 15;
        hm[b * 20 + j] = hprev[b * HIDDEN + jb0 + j];
    }
    if (tid < JB) nhb[tid] = nh_b[jb0 + tid];

    // ---- recurrent weights -> VGPR bf16 B-fragments (one-time) ----
    short8 bw[3][8];
    {
        const int jrow = jb0 + la;
        const int kc = wid << 8;
        const int q8 = (lane >> 4) << 3;
        #pragma unroll
        for (int g = 0; g < 3; ++g) {
            const float* wp = (g == 0 ? rh_w : (g == 1 ? zh_w : nh_w)) + jrow * HIDDEN + kc + q8;
            #pragma unroll
            for (int ks = 0; ks < 8; ++ks) {
                const float* p = wp + ks * 32;
                short8 tv;
                #pragma unroll
                for (int e = 0; e < 8; ++e) tv[e] = (short)f2bf(p[e]);
                bw[g][ks] = tv;
            }
        }
    }
    __syncthreads();

    // ---- the scan ----
    for (int t = 0; t < SEQ; ++t) {
        // A-fragments: 32 x dwordx4 (plain, L2-cached), issued back-to-back
        const char* sb = hs + (size_t)t * SLOT_BYTES;
        short8 af[4][8];
        #pragma unroll
        for (int mt = 0; mt < 4; ++mt) {
            const char* b0 = sb + mt * 8192;
            const char* b1 = b0 + 4096;
            GLD(af[mt][0], b0, "0");
            GLD(af[mt][1], b0, "1024");
            GLD(af[mt][2], b0, "2048");
            GLD(af[mt][3], b0, "3072");
            GLD(af[mt][4], b1, "0");
            GLD(af[mt][5], b1, "1024");
            GLD(af[mt][6], b1, "2048");
            GLD(af[mt][7], b1, "3072");
        }

        // gate-table lookups in the load shadow
        unsigned vs4 = *(const unsigned*)&xs[t * BATCH + ((wid << 4) + ((lane >> 4) << 2))];
        float xrv[4], xzv[4], xnv[4];
        #pragma unroll
        for (int r = 0; r < 4; ++r) {
            int v = (vs4 >> (8 * r)) & 255;
            xrv[r] = tabs[(0 * VOCAB + v) * 17 + la];
            xzv[r] = tabs[(1 * VOCAB + v) * 17 + la];
            xnv[r] = tabs[(2 * VOCAB + v) * 17 + la];
        }
        const float nhbj = nhb[la];

        // wait for all 32 loads; register ties stop MFMA from hoisting above
        asm volatile("s_waitcnt vmcnt(0)"
            : "+v"(af[0][0]), "+v"(af[0][1]), "+v"(af[0][2]), "+v"(af[0][3]),
              "+v"(af[0][4]), "+v"(af[0][5]), "+v"(af[0][6]), "+v"(af[0][7]),
              "+v"(af[1][0]), "+v"(af[1][1]), "+v"(af[1][2]), "+v"(af[1][3]),
              "+v"(af[1][4]), "+v"(af[1][5]), "+v"(af[1][6]), "+v"(af[1][7]));
        asm volatile(""
            : "+v"(af[2][0]), "+v"(af[2][1]), "+v"(af[2][2]), "+v"(af[2][3]),
              "+v"(af[2][4]), "+v"(af[2][5]), "+v"(af[2][6]), "+v"(af[2][7]),
              "+v"(af[3][0]), "+v"(af[3][1]), "+v"(af[3][2]), "+v"(af[3][3]),
              "+v"(af[3][4]), "+v"(af[3][5]), "+v"(af[3][6]), "+v"(af[3][7]));

        f32x4 acc[4][3];
        #pragma unroll
        for (int mt = 0; mt < 4; ++mt)
            #pragma unroll
            for (int g = 0; g < 3; ++g)
                acc[mt][g] = (f32x4){0.f, 0.f, 0.f, 0.f};

        #pragma unroll
        for (int ks = 0; ks < 8; ++ks)
            #pragma unroll
            for (int mt = 0; mt < 4; ++mt) {
                acc[mt][0] = __builtin_amdgcn_mfma_f32_16x16x32_bf16(af[mt][ks], bw[0][ks], acc[mt][0], 0, 0, 0);
                acc[mt][1] = __builtin_amdgcn_mfma_f32_16x16x32_bf16(af[mt][ks], bw[1][ks], acc[mt][1], 0, 0, 0);
                acc[mt][2] = __builtin_amdgcn_mfma_f32_16x16x32_bf16(af[mt][ks], bw[2][ks], acc[mt][2], 0, 0, 0);
            }

        // stash partials, cross-wave reduce (wave w reduces M-tile w)
        #pragma unroll
        for (int mt = 0; mt < 4; ++mt)
            #pragma unroll
            for (int g = 0; g < 3; ++g)
                *(f32x4*)&red[((wid * 12 + g * 4 + mt) * 64 + lane) * 4] = acc[mt][g];
        __syncthreads();                                          // (1)

        f32x4 pre[3];
        #pragma unroll
        for (int g = 0; g < 3; ++g) {
            f32x4 s = *(const f32x4*)&red[((g * 4 + wid) * 64 + lane) * 4];
            #pragma unroll
            for (int w2 = 1; w2 < 4; ++w2)
                s += *(const f32x4*)&red[((w2 * 12 + g * 4 + wid) * 64 + lane) * 4];
            pre[g] = s;
        }

        // gate math: lane cell j = la, b = wid*16 + (lane>>4)*4 + r (C/D layout)
        #pragma unroll
        for (int r = 0; r < 4; ++r) {
            int b = (wid << 4) + ((lane >> 4) << 2) + r;
            float rr = 1.f / (1.f + __expf(-(xrv[r] + pre[0][r])));
            float zz = 1.f / (1.f + __expf(-(xzv[r] + pre[1][r])));
            float ax = xnv[r] + rr * (pre[2][r] + nhbj);
            ax = fminf(15.f, fmaxf(-15.f, ax));
            float e2 = __expf(-2.f * ax);
            float nn = (1.f - e2) / (1.f + e2);
            float ho = hm[b * 20 + la];
            hm[b * 20 + la] = (1.f - zz) * ho + zz * nn;
        }
        __syncthreads();                                          // (2)

        // fragment-layout h-store: 128 threads x one dwordx4, sc1 -> LLC
        if (tid < 128) {
            const float* hp = &hm[srow * 20 + sjj];
            f32x4 h0 = *(const f32x4*)(hp);
            f32x4 h1 = *(const f32x4*)(hp + 4);
            u32x4 pk;
            pk[0] = (unsigned)f2bf(h0[0]) | ((unsigned)f2bf(h0[1]) << 16);
            pk[1] = (unsigned)f2bf(h0[2]) | ((unsigned)f2bf(h0[3]) << 16);
            pk[2] = (unsigned)f2bf(h1[0]) | ((unsigned)f2bf(h1[1]) << 16);
            pk[3] = (unsigned)f2bf(h1[2]) | ((unsigned)f2bf(h1[3]) << 16);
            const char* db = hs + (size_t)(t + 1) * SLOT_BYTES;
            asm volatile("global_store_dwordx4 %0, %1, %2 sc1"
                         :: "v"(sva), "v"(pk), "s"(db) : "memory");
        }

        // grid barrier: drain stores, flag store (sc1), all-poll-all on 64 flags
        asm volatile("s_waitcnt vmcnt(0)" ::: "memory");
        __syncthreads();                                          // (3)
        const unsigned tgt = (unsigned)(t + 1);
        if (tid == 0)
            __hip_atomic_store(&flags[blockIdx.x], tgt, __ATOMIC_RELAXED, __HIP_MEMORY_SCOPE_AGENT);
        if (wid == 0) {
            u64 bal;
            do {
                unsigned v = __hip_atomic_load(&flags[lane], __ATOMIC_RELAXED, __HIP_MEMORY_SCOPE_AGENT);
                bal = __ballot(v >= tgt);
            } while (bal != ~0ull);
        }
        __syncthreads();                                          // (4)
    }

    for (int i = tid; i < BATCH * JB; i += 256) {
        int b = i >> 4, j = i & 15;
        hfin[b * HIDDEN + jb0 + j] = hm[b * 20 + j];
    }
}

// ---------------- logits head: hs (fragment layout) @ dense_w^T -----------
__global__ __launch_bounds__(256) void logits_kernel(const char* __restrict__ hs,
                                                     const ushort_t* __restrict__ dwbf,
                                                     const float* __restrict__ db,
                                                     float* __restrict__ out) {
    const int tid = threadIdx.x, wid = tid >> 6, lane = tid & 63;
    const int la = lane & 15, q8 = (lane >> 4) << 3;
    const int i0 = blockIdx.x << 7;                   // 128 rows/block
    const int R0 = i0 + wid * 32;
    const int R1 = R0 + 16;
    const char* s0 = hs + (size_t)((R0 >> 6) + 1) * SLOT_BYTES;
    const char* s1 = hs + (size_t)((R1 >> 6) + 1) * SLOT_BYTES;
    const int mtb0 = (R0 >> 4) & 3;
    const int mtb1 = (R1 >> 4) & 3;

    f32x4 acc[2][8];
    #pragma unroll
    for (int mi = 0; mi < 2; ++mi)
        #pragma unroll
        for (int nt = 0; nt < 8; ++nt) acc[mi][nt] = (f32x4){0.f, 0.f, 0.f, 0.f};

    for (int ks2 = 0; ks2 < 32; ++ks2) {
        const int w = ks2 >> 3, ks = ks2 & 7;
        short8 a0 = *(const short8*)(s0 + (size_t)((((w * 4 + mtb0) * 8 + ks) * 64) + lane) * 16);
        short8 a1 = *(const short8*)(s1 + (size_t)((((w * 4 + mtb1) * 8 + ks) * 64) + lane) * 16);
        const int k = ks2 * 32 + q8;
        #pragma unroll
        for (int nt = 0; nt < 8; ++nt) {
            short8 bb = *(const short8*)(dwbf + (nt * 16 + la) * HIDDEN + k);
            acc[0][nt] = __builtin_amdgcn_mfma_f32_16x16x32_bf16(a0, bb, acc[0][nt], 0, 0, 0);
            acc[1][nt] = __builtin_amdgcn_mfma_f32_16x16x32_bf16(a1, bb, acc[1][nt], 0, 0, 0);
        }
    }
    #pragma unroll
    for (int mi = 0; mi < 2; ++mi)
        #pragma unroll
        for (int nt = 0; nt < 8; ++nt) {
            int col = nt * 16 + la;
            float bias = db[col];
            int Rb = (mi == 0 ? R0 : R1) + ((lane >> 4) << 2);
            #pragma unroll
            for (int r = 0; r < 4; ++r)
                out[(size_t)(Rb + r) * VOCAB + col] = acc[mi][nt][r] + bias;
        }
}

// ---------------- launch ---------------------------------------------------
extern "C" void kernel_launch(void* const* d_in, const int* in_sizes, int n_in,
                              void* d_out, int out_size, void* d_ws, size_t ws_size,
                              hipStream_t stream) {
    const int*   x       = (const int*)d_in[0];
    const float* hprev   = (const float*)d_in[1];
    const float* emb     = (const float*)d_in[2];
    const float* rx_w    = (const float*)d_in[3];
    const float* rx_b    = (const float*)d_in[4];
    const float* rh_w    = (const float*)d_in[5];
    const float* rh_b    = (const float*)d_in[6];
    const float* zx_w    = (const float*)d_in[7];
    const float* zx_b    = (const float*)d_in[8];
    const float* zh_w    = (const float*)d_in[9];
    const float* zh_b    = (const float*)d_in[10];
    const float* nx_w    = (const float*)d_in[11];
    const float* nx_b    = (const float*)d_in[12];
    const float* nh_w    = (const float*)d_in[13];
    const float* nh_b    = (const float*)d_in[14];
    const float* dense_w = (const float*)d_in[15];
    const float* dense_b = (const float*)d_in[16];

    char* ws = (char*)d_ws;
    unsigned* flags = (unsigned*)ws;                 // 64 words
    float*    xall  = (float*)(ws + OFF_XALL);
    ushort_t* dwbf  = (ushort_t*)(ws + OFF_DWBF);
    char*     hs    = ws + OFF_HS;                   // (SEQ+1) fragment-layout slots
    float* out  = (float*)d_out;
    float* hfin = out + (size_t)SEQ * BATCH * VOCAB;

    init_kernel<<<512, 256, 0, stream>>>(hprev, dense_w, hs, dwbf, flags);
    tables_kernel<<<1536, 256, 0, stream>>>(emb, rx_w, rx_b, rh_b, zx_w, zx_b, zh_b,
                                            nx_w, nx_b, xall);
    const int lds_bytes = 3*VOCAB*17*4 + BATCH*20*4 + SEQ*BATCH + 12288*4 + 16*4; // 96832
    hipFuncSetAttribute((const void*)gru_kernel,
                        hipFuncAttributeMaxDynamicSharedMemorySize, lds_bytes);
    gru_kernel<<<NWG, 256, lds_bytes, stream>>>(x, hprev, rh_w, zh_w, nh_w, nh_b,
                                                xall, hs, flags, hfin);
    logits_kernel<<<128, 256, 0, stream>>>(hs, dwbf, dense_b, out);
}

// Round 6
// 1220.511 us; speedup vs baseline: 1.3630x; 1.3630x over previous
//
#include <hip/hip_runtime.h>

typedef __attribute__((ext_vector_type(8))) short short8;
typedef __attribute__((ext_vector_type(4))) float f32x4;
typedef __attribute__((ext_vector_type(4))) unsigned int u32x4;
typedef unsigned short ushort_t;
typedef unsigned long long u64;

#define SEQ    256
#define BATCH  64
#define VOCAB  128
#define EMBED  256
#define HIDDEN 1024
#define NWG    64
#define JB     16
#define BH     (BATCH * HIDDEN)
#define SLOT_BYTES 131072                 // one h slot = 64x1024 bf16 = 8192 x 16B units

// workspace layout (bytes)
#define OFF_XALL 16384                    // flags: 64 lines x 128 B = 8 KB (+pad)
#define OFF_DWBF (OFF_XALL + 3*VOCAB*HIDDEN*4)
#define OFF_HS   (OFF_DWBF + VOCAB*HIDDEN*2)     // (SEQ+1) slots, 16B-unit fragment layout

__device__ __forceinline__ ushort_t f2bf(float f) {
    unsigned u = __float_as_uint(f);
    u += 0x7FFFu + ((u >> 16) & 1u);          // RNE
    return (ushort_t)(u >> 16);
}

// 16B-unit fragment layout: unit P = ((w*4+mt)*8+ks)*64 + (q*16+la)
// holds rows mt*16+la, k = w*256 + ks*32 + q*8 + (0..7)   (8 bf16 = 16 B)

// ---------------- init: hs[0]=bf16(hprev) frag-layout, dwbf, flags=0 ------
__global__ __launch_bounds__(256) void init_kernel(const float* __restrict__ hprev,
                                                   const float* __restrict__ dense_w,
                                                   char* __restrict__ hs,
                                                   ushort_t* __restrict__ dwbf,
                                                   unsigned* __restrict__ flags) {
    int i = blockIdx.x * 256 + threadIdx.x;
    if (i < 64) __hip_atomic_store(&flags[i * 32], 0u, __ATOMIC_RELAXED, __HIP_MEMORY_SCOPE_AGENT);
    if (i < 8192) {
        int lane = i & 63, plane = i >> 6;
        int ks = plane & 7, mt = (plane >> 3) & 3, w = plane >> 5;
        int la = lane & 15, q = lane >> 4;
        int row = mt * 16 + la;
        int k   = w * 256 + ks * 32 + q * 8;
        const float* hp = hprev + row * HIDDEN + k;
        ushort_t* dst = (ushort_t*)(hs + (size_t)i * 16);
        #pragma unroll
        for (int e = 0; e < 8; ++e) dst[e] = f2bf(hp[e]);
    }
    if (i < VOCAB * HIDDEN) dwbf[i] = f2bf(dense_w[i]);
}

// ---------------- tables: xall[g][v][j] = emb[v]·w_g[j] + folded biases ----
__global__ __launch_bounds__(256) void tables_kernel(const float* __restrict__ emb,
    const float* __restrict__ rx_w, const float* __restrict__ rx_b, const float* __restrict__ rh_b,
    const float* __restrict__ zx_w, const float* __restrict__ zx_b, const float* __restrict__ zh_b,
    const float* __restrict__ nx_w, const float* __restrict__ nx_b,
    float* __restrict__ xall) {
    int id = blockIdx.x * 256 + threadIdx.x;          // id = (g*128+v)*1024 + j
    int j  = id & (HIDDEN - 1);
    int vg = id >> 10;
    int v  = vg & (VOCAB - 1);
    int g  = vg >> 7;
    const float* w = (g == 0 ? rx_w : (g == 1 ? zx_w : nx_w)) + j * EMBED;
    const float* e = emb + v * EMBED;
    float acc = 0.f;
    #pragma unroll 8
    for (int t = 0; t < EMBED; t += 4) {
        acc = fmaf(e[t+0], w[t+0], acc);
        acc = fmaf(e[t+1], w[t+1], acc);
        acc = fmaf(e[t+2], w[t+2], acc);
        acc = fmaf(e[t+3], w[t+3], acc);
    }
    float bias = (g == 0) ? (rx_b[j] + rh_b[j]) : ((g == 1) ? (zx_b[j] + zh_b[j]) : nx_b[j]);
    xall[id] = acc + bias;
}

// A-loads: plain (L2-cached) 16B loads — 8 WGs/XCD share the broadcast via
// their XCD L2; values are write-once per launch and launch-deterministic.
#define GLD(dst, base, OFF) \
    asm volatile("global_load_dwordx4 %0, %1, %2 offset:" OFF \
                 : "=v"(dst) : "v"(va), "s"(base) : "memory")

// ---------------- persistent GRU scan -------------------------------------
__global__ __launch_bounds__(256, 1) void gru_kernel(
    const int* __restrict__ x, const float* __restrict__ hprev,
    const float* __restrict__ rh_w, const float* __restrict__ zh_w,
    const float* __restrict__ nh_w, const float* __restrict__ nh_b,
    const float* __restrict__ xall,
    char* __restrict__ hs, unsigned* flags, float* __restrict__ hfin)
{
    extern __shared__ char smem[];
    float* tabs = (float*)smem;                       // [3][128][17]  26112 B
    float* hm   = tabs + 3 * VOCAB * 17;              // [64][20]       5120 B
    unsigned char* xs = (unsigned char*)(hm + BATCH * 20);   // 16384 B
    float* red  = (float*)(xs + SEQ * BATCH);         // 12288 floats  49152 B
    float* nhb  = red + 12288;                        // 16 floats

    const int tid  = threadIdx.x;
    const int wid  = tid >> 6;
    const int lane = tid & 63;
    const int jb0  = blockIdx.x * JB;
    const int la   = lane & 15;
    // WG's column region in fragment coords
    const int w0  = jb0 >> 8;
    const int ks0 = (jb0 >> 5) & 7;
    const int q0  = (jb0 >> 3) & 3;                   // 0 or 2

    // store-phase decode (tid<128): thread -> 16B unit (row smt*16+sla, 8 cols)
    const int smt = tid >> 5;                         // 0..3
    const int sqq = (tid >> 4) & 1;                   // 0..1
    const int sla = tid & 15;
    const int srow = smt * 16 + sla;
    const int sjj  = sqq * 8;                         // local col base
    const unsigned sva = (unsigned)((((w0 * 4 + smt) * 8 + ks0) * 64
                                     + (q0 + sqq) * 16 + sla) * 16);

    // A-load vaddr (byte): lane*16 + wid*32768
    const unsigned va = (unsigned)((wid << 15) | (lane << 4));

    // this wave's producer-group flag pointer (one flag per 128-B line)
    unsigned* myflag = flags + ((wid << 4) + la) * 32;   // la in 0..15 pattern below
    unsigned* pollp  = flags + (((wid << 4) + (lane & 15)) << 5);

    // ---- prologue: LDS fills ----
    for (int i = tid; i < 3 * VOCAB * JB; i += 256) {
        int g = i >> 11, rem = i & 2047, v = rem >> 4, j = rem & 15;
        tabs[(g * VOCAB + v) * 17 + j] = xall[(g * VOCAB + v) * HIDDEN + jb0 + j];
    }
    for (int i = tid; i < SEQ * BATCH; i += 256) xs[i] = (unsigned char)x[i];
    for (int i = tid; i < BATCH * JB; i += 256) {
        int b = i >> 4, j = i & 15;
        hm[b * 20 + j] = hprev[b * HIDDEN + jb0 + j];
    }
    if (tid < JB) nhb[tid] = nh_b[jb0 + tid];

    // ---- recurrent weights -> VGPR bf16 B-fragments (one-time) ----
    short8 bw[3][8];
    {
        const int jrow = jb0 + la;
        const int kc = wid << 8;
        const int q8 = (lane >> 4) << 3;
        #pragma unroll
        for (int g = 0; g < 3; ++g) {
            const float* wp = (g == 0 ? rh_w : (g == 1 ? zh_w : nh_w)) + jrow * HIDDEN + kc + q8;
            #pragma unroll
            for (int ks = 0; ks < 8; ++ks) {
                const float* p = wp + ks * 32;
                short8 tv;
                #pragma unroll
                for (int e = 0; e < 8; ++e) tv[e] = (short)f2bf(p[e]);
                bw[g][ks] = tv;
            }
        }
    }
    __syncthreads();

    // ---- the scan ----
    for (int t = 0; t < SEQ; ++t) {
        // wave-level dependency wait: wave w needs only producers 16w..16w+15
        if (t > 0) {
            const unsigned tgt = (unsigned)t;
            unsigned v = __hip_atomic_load(pollp, __ATOMIC_RELAXED, __HIP_MEMORY_SCOPE_AGENT);
            while (__ballot(v >= tgt) != ~0ull) {
                __builtin_amdgcn_s_sleep(2);
                v = __hip_atomic_load(pollp, __ATOMIC_RELAXED, __HIP_MEMORY_SCOPE_AGENT);
            }
        }

        // A-fragments: 32 x dwordx4 (plain, L2-cached), issued back-to-back
        const char* sb = hs + (size_t)t * SLOT_BYTES;
        short8 af[4][8];
        #pragma unroll
        for (int mt = 0; mt < 4; ++mt) {
            const char* b0 = sb + mt * 8192;
            const char* b1 = b0 + 4096;
            GLD(af[mt][0], b0, "0");
            GLD(af[mt][1], b0, "1024");
            GLD(af[mt][2], b0, "2048");
            GLD(af[mt][3], b0, "3072");
            GLD(af[mt][4], b1, "0");
            GLD(af[mt][5], b1, "1024");
            GLD(af[mt][6], b1, "2048");
            GLD(af[mt][7], b1, "3072");
        }

        // gate-table lookups in the load shadow
        unsigned vs4 = *(const unsigned*)&xs[t * BATCH + ((wid << 4) + ((lane >> 4) << 2))];
        float xrv[4], xzv[4], xnv[4];
        #pragma unroll
        for (int r = 0; r < 4; ++r) {
            int v = (vs4 >> (8 * r)) & 255;
            xrv[r] = tabs[(0 * VOCAB + v) * 17 + la];
            xzv[r] = tabs[(1 * VOCAB + v) * 17 + la];
            xnv[r] = tabs[(2 * VOCAB + v) * 17 + la];
        }
        const float nhbj = nhb[la];

        // wait for all 32 loads; register ties stop MFMA from hoisting above
        asm volatile("s_waitcnt vmcnt(0)"
            : "+v"(af[0][0]), "+v"(af[0][1]), "+v"(af[0][2]), "+v"(af[0][3]),
              "+v"(af[0][4]), "+v"(af[0][5]), "+v"(af[0][6]), "+v"(af[0][7]),
              "+v"(af[1][0]), "+v"(af[1][1]), "+v"(af[1][2]), "+v"(af[1][3]),
              "+v"(af[1][4]), "+v"(af[1][5]), "+v"(af[1][6]), "+v"(af[1][7]));
        asm volatile(""
            : "+v"(af[2][0]), "+v"(af[2][1]), "+v"(af[2][2]), "+v"(af[2][3]),
              "+v"(af[2][4]), "+v"(af[2][5]), "+v"(af[2][6]), "+v"(af[2][7]),
              "+v"(af[3][0]), "+v"(af[3][1]), "+v"(af[3][2]), "+v"(af[3][3]),
              "+v"(af[3][4]), "+v"(af[3][5]), "+v"(af[3][6]), "+v"(af[3][7]));

        f32x4 acc[4][3];
        #pragma unroll
        for (int mt = 0; mt < 4; ++mt)
            #pragma unroll
            for (int g = 0; g < 3; ++g)
                acc[mt][g] = (f32x4){0.f, 0.f, 0.f, 0.f};

        #pragma unroll
        for (int ks = 0; ks < 8; ++ks)
            #pragma unroll
            for (int mt = 0; mt < 4; ++mt) {
                acc[mt][0] = __builtin_amdgcn_mfma_f32_16x16x32_bf16(af[mt][ks], bw[0][ks], acc[mt][0], 0, 0, 0);
                acc[mt][1] = __builtin_amdgcn_mfma_f32_16x16x32_bf16(af[mt][ks], bw[1][ks], acc[mt][1], 0, 0, 0);
                acc[mt][2] = __builtin_amdgcn_mfma_f32_16x16x32_bf16(af[mt][ks], bw[2][ks], acc[mt][2], 0, 0, 0);
            }

        // stash partials, cross-wave reduce (wave w reduces M-tile w)
        #pragma unroll
        for (int mt = 0; mt < 4; ++mt)
            #pragma unroll
            for (int g = 0; g < 3; ++g)
                *(f32x4*)&red[((wid * 12 + g * 4 + mt) * 64 + lane) * 4] = acc[mt][g];
        __syncthreads();                                          // (1)

        f32x4 pre[3];
        #pragma unroll
        for (int g = 0; g < 3; ++g) {
            f32x4 s = *(const f32x4*)&red[((g * 4 + wid) * 64 + lane) * 4];
            #pragma unroll
            for (int w2 = 1; w2 < 4; ++w2)
                s += *(const f32x4*)&red[((w2 * 12 + g * 4 + wid) * 64 + lane) * 4];
            pre[g] = s;
        }

        // gate math: lane cell j = la, b = wid*16 + (lane>>4)*4 + r (C/D layout)
        #pragma unroll
        for (int r = 0; r < 4; ++r) {
            int b = (wid << 4) + ((lane >> 4) << 2) + r;
            float rr = 1.f / (1.f + __expf(-(xrv[r] + pre[0][r])));
            float zz = 1.f / (1.f + __expf(-(xzv[r] + pre[1][r])));
            float ax = xnv[r] + rr * (pre[2][r] + nhbj);
            ax = fminf(15.f, fmaxf(-15.f, ax));
            float e2 = __expf(-2.f * ax);
            float nn = (1.f - e2) / (1.f + e2);
            float ho = hm[b * 20 + la];
            hm[b * 20 + la] = (1.f - zz) * ho + zz * nn;
        }
        __syncthreads();                                          // (2)

        // fragment-layout h-store: 128 threads x one dwordx4, sc1 -> LLC
        if (tid < 128) {
            const float* hp = &hm[srow * 20 + sjj];
            f32x4 h0 = *(const f32x4*)(hp);
            f32x4 h1 = *(const f32x4*)(hp + 4);
            u32x4 pk;
            pk[0] = (unsigned)f2bf(h0[0]) | ((unsigned)f2bf(h0[1]) << 16);
            pk[1] = (unsigned)f2bf(h0[2]) | ((unsigned)f2bf(h0[3]) << 16);
            pk[2] = (unsigned)f2bf(h1[0]) | ((unsigned)f2bf(h1[1]) << 16);
            pk[3] = (unsigned)f2bf(h1[2]) | ((unsigned)f2bf(h1[3]) << 16);
            const char* db = hs + (size_t)(t + 1) * SLOT_BYTES;
            asm volatile("global_store_dwordx4 %0, %1, %2 sc1"
                         :: "v"(sva), "v"(pk), "s"(db) : "memory");
        }

        // publish: drain own stores, barrier, then single flag store (own line)
        asm volatile("s_waitcnt vmcnt(0)" ::: "memory");
        __syncthreads();                                          // (3)
        if (tid == 0)
            __hip_atomic_store(&flags[blockIdx.x * 32], (unsigned)(t + 1),
                               __ATOMIC_RELAXED, __HIP_MEMORY_SCOPE_AGENT);
    }

    __syncthreads();
    for (int i = tid; i < BATCH * JB; i += 256) {
        int b = i >> 4, j = i & 15;
        hfin[b * HIDDEN + jb0 + j] = hm[b * 20 + j];
    }
    (void)myflag;
}

// ---------------- logits head: hs (fragment layout) @ dense_w^T -----------
__global__ __launch_bounds__(256) void logits_kernel(const char* __restrict__ hs,
                                                     const ushort_t* __restrict__ dwbf,
                                                     const float* __restrict__ db,
                                                     float* __restrict__ out) {
    const int tid = threadIdx.x, wid = tid >> 6, lane = tid & 63;
    const int la = lane & 15, q8 = (lane >> 4) << 3;
    const int i0 = blockIdx.x << 7;                   // 128 rows/block
    const int R0 = i0 + wid * 32;
    const int R1 = R0 + 16;
    const char* s0 = hs + (size_t)((R0 >> 6) + 1) * SLOT_BYTES;
    const char* s1 = hs + (size_t)((R1 >> 6) + 1) * SLOT_BYTES;
    const int mtb0 = (R0 >> 4) & 3;
    const int mtb1 = (R1 >> 4) & 3;

    f32x4 acc[2][8];
    #pragma unroll
    for (int mi = 0; mi < 2; ++mi)
        #pragma unroll
        for (int nt = 0; nt < 8; ++nt) acc[mi][nt] = (f32x4){0.f, 0.f, 0.f, 0.f};

    for (int ks2 = 0; ks2 < 32; ++ks2) {
        const int w = ks2 >> 3, ks = ks2 & 7;
        short8 a0 = *(const short8*)(s0 + (size_t)((((w * 4 + mtb0) * 8 + ks) * 64) + lane) * 16);
        short8 a1 = *(const short8*)(s1 + (size_t)((((w * 4 + mtb1) * 8 + ks) * 64) + lane) * 16);
        const int k = ks2 * 32 + q8;
        #pragma unroll
        for (int nt = 0; nt < 8; ++nt) {
            short8 bb = *(const short8*)(dwbf + (nt * 16 + la) * HIDDEN + k);
            acc[0][nt] = __builtin_amdgcn_mfma_f32_16x16x32_bf16(a0, bb, acc[0][nt], 0, 0, 0);
            acc[1][nt] = __builtin_amdgcn_mfma_f32_16x16x32_bf16(a1, bb, acc[1][nt], 0, 0, 0);
        }
    }
    #pragma unroll
    for (int mi = 0; mi < 2; ++mi)
        #pragma unroll
        for (int nt = 0; nt < 8; ++nt) {
            int col = nt * 16 + la;
            float bias = db[col];
            int Rb = (mi == 0 ? R0 : R1) + ((lane >> 4) << 2);
            #pragma unroll
            for (int r = 0; r < 4; ++r)
                out[(size_t)(Rb + r) * VOCAB + col] = acc[mi][nt][r] + bias;
        }
}

// ---------------- launch ---------------------------------------------------
extern "C" void kernel_launch(void* const* d_in, const int* in_sizes, int n_in,
                              void* d_out, int out_size, void* d_ws, size_t ws_size,
                              hipStream_t stream) {
    const int*   x       = (const int*)d_in[0];
    const float* hprev   = (const float*)d_in[1];
    const float* emb     = (const float*)d_in[2];
    const float* rx_w    = (const float*)d_in[3];
    const float* rx_b    = (const float*)d_in[4];
    const float* rh_w    = (const float*)d_in[5];
    const float* rh_b    = (const float*)d_in[6];
    const float* zx_w    = (const float*)d_in[7];
    const float* zx_b    = (const float*)d_in[8];
    const float* zh_w    = (const float*)d_in[9];
    const float* zh_b    = (const float*)d_in[10];
    const float* nx_w    = (const float*)d_in[11];
    const float* nx_b    = (const float*)d_in[12];
    const float* nh_w    = (const float*)d_in[13];
    const float* nh_b    = (const float*)d_in[14];
    const float* dense_w = (const float*)d_in[15];
    const float* dense_b = (const float*)d_in[16];

    char* ws = (char*)d_ws;
    unsigned* flags = (unsigned*)ws;                 // 64 flags, one per 128-B line
    float*    xall  = (float*)(ws + OFF_XALL);
    ushort_t* dwbf  = (ushort_t*)(ws + OFF_DWBF);
    char*     hs    = ws + OFF_HS;                   // (SEQ+1) fragment-layout slots
    float* out  = (float*)d_out;
    float* hfin = out + (size_t)SEQ * BATCH * VOCAB;

    init_kernel<<<512, 256, 0, stream>>>(hprev, dense_w, hs, dwbf, flags);
    tables_kernel<<<1536, 256, 0, stream>>>(emb, rx_w, rx_b, rh_b, zx_w, zx_b, zh_b,
                                            nx_w, nx_b, xall);
    const int lds_bytes = 3*VOCAB*17*4 + BATCH*20*4 + SEQ*BATCH + 12288*4 + 16*4; // 96832
    hipFuncSetAttribute((const void*)gru_kernel,
                        hipFuncAttributeMaxDynamicSharedMemorySize, lds_bytes);
    gru_kernel<<<NWG, 256, lds_bytes, stream>>>(x, hprev, rh_w, zh_w, nh_w, nh_b,
                                                xall, hs, flags, hfin);
    logits_kernel<<<128, 256, 0, stream>>>(hs, dwbf, dense_b, out);
}